// Round 2
// baseline (124.712 us; speedup 1.0000x reference)
//
#include <hip/hip_runtime.h>

#define DIM 4096
#define R 8

// ws layout: S = G^{-1} at ws[0..63]; T (4096x8) at ws+64
#define T_OFF 64

// ---------------------------------------------------------------------------
// K1: one block, 256 threads. G = A^T A (8x8), then S = G^{-1} via
// Gauss-Jordan on wave 0 (lane t holds element (t>>3, t&7)).
// ---------------------------------------------------------------------------
__global__ __launch_bounds__(256) void gram_inv_kernel(const float* __restrict__ A,
                                                       float* __restrict__ S) {
    __shared__ float gsh[4][64];
    const int t = threadIdx.x;
    const int wave = t >> 6, lane = t & 63;
    const float4* A4 = (const float4*)A;

    float acc[R][R];
#pragma unroll
    for (int a = 0; a < R; ++a)
#pragma unroll
        for (int b = 0; b < R; ++b) acc[a][b] = 0.f;

#pragma unroll
    for (int it = 0; it < DIM / 256; ++it) {
        const int j = it * 256 + t;
        float4 lo = A4[j * 2 + 0];
        float4 hi = A4[j * 2 + 1];
        float u[R] = {lo.x, lo.y, lo.z, lo.w, hi.x, hi.y, hi.z, hi.w};
#pragma unroll
        for (int a = 0; a < R; ++a)
#pragma unroll
            for (int b = 0; b < R; ++b) acc[a][b] += u[a] * u[b];
    }

    // wave-level butterfly: every lane gets its wave's sum
#pragma unroll
    for (int a = 0; a < R; ++a)
#pragma unroll
        for (int b = 0; b < R; ++b) {
            float v = acc[a][b];
#pragma unroll
            for (int off = 32; off >= 1; off >>= 1) v += __shfl_xor(v, off, 64);
            acc[a][b] = v;
        }

    // lane i of each wave deposits element i (static predicated writes)
#pragma unroll
    for (int a = 0; a < R; ++a)
#pragma unroll
        for (int b = 0; b < R; ++b)
            if (lane == a * 8 + b) gsh[wave][a * 8 + b] = acc[a][b];
    __syncthreads();

    if (wave == 0) {
        const int r_ = lane >> 3, c_ = lane & 7;
        float M = gsh[0][lane] + gsh[1][lane] + gsh[2][lane] + gsh[3][lane];
        float E = (r_ == c_) ? 1.f : 0.f;
        // Gauss-Jordan, no pivoting (G is SPD, kappa ~ 1)
#pragma unroll
        for (int k = 0; k < R; ++k) {
            float piv  = __shfl(M, k * 8 + k, 64);
            float pinv = 1.0f / piv;
            float Mkc  = __shfl(M, k * 8 + c_, 64) * pinv;
            float Ekc  = __shfl(E, k * 8 + c_, 64) * pinv;
            float Mrk  = __shfl(M, r_ * 8 + k, 64);
            bool  isk  = (r_ == k);
            M = isk ? Mkc : (M - Mrk * Mkc);
            E = isk ? Ekc : (E - Mrk * Ekc);
        }
        S[lane] = E;
    }
}

// ---------------------------------------------------------------------------
// K2: T = 2 * (W @ A) @ S.  4 rows per block, 1024 blocks x 256 threads.
// Streams W once; short reduction tail.
// ---------------------------------------------------------------------------
__global__ __launch_bounds__(256) void dot_kernel(const float* __restrict__ W,
                                                  const float* __restrict__ A,
                                                  const float* __restrict__ S,
                                                  float* __restrict__ T) {
    __shared__ float red[4][32];
    __shared__ float sb[32];
    const int t = threadIdx.x;
    const int wave = t >> 6, lane = t & 63;
    const int row0 = blockIdx.x * 4;
    const float4* W4 = (const float4*)W;
    const float4* A4 = (const float4*)A;

    float p[4][R];
#pragma unroll
    for (int r = 0; r < 4; ++r)
#pragma unroll
        for (int k = 0; k < R; ++k) p[r][k] = 0.f;

#pragma unroll
    for (int c = 0; c < 4; ++c) {
        float4 w[4];
#pragma unroll
        for (int r = 0; r < 4; ++r)
            w[r] = W4[(size_t)(row0 + r) * (DIM / 4) + c * 256 + t];
#pragma unroll
        for (int jj = 0; jj < 4; ++jj) {
            const int j = (c * 256 + t) * 4 + jj;
            float4 alo = A4[j * 2 + 0];
            float4 ahi = A4[j * 2 + 1];
#pragma unroll
            for (int r = 0; r < 4; ++r) {
                const float wv = ((const float*)&w[r])[jj];
                p[r][0] += wv * alo.x; p[r][1] += wv * alo.y;
                p[r][2] += wv * alo.z; p[r][3] += wv * alo.w;
                p[r][4] += wv * ahi.x; p[r][5] += wv * ahi.y;
                p[r][6] += wv * ahi.z; p[r][7] += wv * ahi.w;
            }
        }
    }

#pragma unroll
    for (int r = 0; r < 4; ++r)
#pragma unroll
        for (int k = 0; k < R; ++k) {
            float v = p[r][k];
#pragma unroll
            for (int off = 32; off >= 1; off >>= 1) v += __shfl_xor(v, off, 64);
            p[r][k] = v;
        }

#pragma unroll
    for (int i = 0; i < 32; ++i)
        if (lane == i) red[wave][i] = p[i / R][i % R];
    __syncthreads();

    if (t < 32) sb[t] = red[0][t] + red[1][t] + red[2][t] + red[3][t];
    __syncthreads();

    if (t < 32) {
        const int r = t >> 3, k = t & 7;
        float a = 0.f;
#pragma unroll
        for (int m = 0; m < R; ++m) a += S[k * R + m] * sb[r * R + m];
        T[(size_t)(row0 + r) * R + k] = 2.0f * a;
    }
}

// ---------------------------------------------------------------------------
// K3: out = W - T . A^T.  Pure streaming, no barriers. Tile = 32 rows x 256
// cols; 2048 blocks x 256 threads; each thread: A-fragment in regs, 8 rows.
// ---------------------------------------------------------------------------
__global__ __launch_bounds__(256) void apply_kernel(const float* __restrict__ W,
                                                    const float* __restrict__ A,
                                                    const float* __restrict__ T,
                                                    float* __restrict__ out) {
    const int t = threadIdx.x;
    const int wave = t >> 6, lane = t & 63;
    const int bid = blockIdx.x;
    const int tr = bid >> 4;     // 128 row-tiles of 32
    const int tc = bid & 15;     // 16 col-tiles of 256
    const int c4 = tc * 64 + lane;  // float4 column index [0,1024)

    const float4* A4 = (const float4*)A;
    const float4* W4 = (const float4*)W;
    const float4* T4 = (const float4*)T;
    float4* O4 = (float4*)out;

    float4 alo[4], ahi[4];
#pragma unroll
    for (int jj = 0; jj < 4; ++jj) {
        const int j = c4 * 4 + jj;
        alo[jj] = A4[j * 2 + 0];
        ahi[jj] = A4[j * 2 + 1];
    }

    const int row0 = tr * 32 + wave * 8;
#pragma unroll
    for (int rr = 0; rr < 8; ++rr) {
        const int row = row0 + rr;
        float4 t01 = T4[(size_t)row * 2 + 0];   // T[row][0..3]
        float4 t23 = T4[(size_t)row * 2 + 1];   // T[row][4..7]
        float4 w4 = W4[(size_t)row * (DIM / 4) + c4];
        float o[4];
#pragma unroll
        for (int jj = 0; jj < 4; ++jj) {
            float d = t01.x * alo[jj].x + t01.y * alo[jj].y +
                      t01.z * alo[jj].z + t01.w * alo[jj].w +
                      t23.x * ahi[jj].x + t23.y * ahi[jj].y +
                      t23.z * ahi[jj].z + t23.w * ahi[jj].w;
            o[jj] = ((const float*)&w4)[jj] - d;
        }
        O4[(size_t)row * (DIM / 4) + c4] = make_float4(o[0], o[1], o[2], o[3]);
    }
}

extern "C" void kernel_launch(void* const* d_in, const int* in_sizes, int n_in,
                              void* d_out, int out_size, void* d_ws, size_t ws_size,
                              hipStream_t stream) {
    const float* W = (const float*)d_in[0];    // [4096][4096] f32
    const float* A = (const float*)d_in[1];    // [4096][8]    f32
    float* out = (float*)d_out;                // [4096][4096] f32
    float* S = (float*)d_ws;                   // 64 floats
    float* T = (float*)d_ws + T_OFF;           // 4096*8 floats

    gram_inv_kernel<<<1, 256, 0, stream>>>(A, S);
    dot_kernel<<<DIM / 4, 256, 0, stream>>>(W, A, S, T);
    apply_kernel<<<2048, 256, 0, stream>>>(W, A, T, out);
}